// Round 1
// baseline (7763.088 us; speedup 1.0000x reference)
//
#include <hip/hip_runtime.h>

// Problem constants (from reference)
#define B_N   262144
#define D_N   16
#define C_N   8
#define H_N   128
#define K_N   10
#define L_N   4
#define DOUT_N 248      // (3K+1)*D2
#define PMIN_F 0.001f

// Thread-per-row fp32 baseline. 64 threads/WG (1 wave).
// h1/h2 staged in LDS as f16 in [neuron][lane] layout (2-way bank aliasing = free).
// Weight loads are wave-uniform -> scalar loads via K$.
__global__ __launch_bounds__(64) void flow_kernel(
    const float* __restrict__ x_in,
    const float* __restrict__ c_in,
    const float* __restrict__ W1s,
    const float* __restrict__ b1s,
    const float* __restrict__ Whs,
    const float* __restrict__ bhs,
    const float* __restrict__ Wos,
    const float* __restrict__ bos,
    const int*   __restrict__ perms,
    float* __restrict__ out)
{
    __shared__ _Float16 h1s[H_N][64];
    __shared__ _Float16 h2s[H_N][64];
    __shared__ float    xbuf[D_N][64];

    const int t = threadIdx.x;
    const long long r = (long long)blockIdx.x * 64 + t;

    float xr[D_N];
    {
        const float4* xp = (const float4*)(x_in + r * D_N);
        float4 a = xp[0], b = xp[1], cc = xp[2], d = xp[3];
        xr[0]=a.x;  xr[1]=a.y;  xr[2]=a.z;  xr[3]=a.w;
        xr[4]=b.x;  xr[5]=b.y;  xr[6]=b.z;  xr[7]=b.w;
        xr[8]=cc.x; xr[9]=cc.y; xr[10]=cc.z; xr[11]=cc.w;
        xr[12]=d.x; xr[13]=d.y; xr[14]=d.z; xr[15]=d.w;
    }
    float cr[C_N];
    {
        const float4* cp = (const float4*)(c_in + r * C_N);
        float4 a = cp[0], b = cp[1];
        cr[0]=a.x; cr[1]=a.y; cr[2]=a.z; cr[3]=a.w;
        cr[4]=b.x; cr[5]=b.y; cr[6]=b.z; cr[7]=b.w;
    }

    float ljd = 0.f;

    for (int l = 0; l < L_N; ++l) {
        const float* W1 = W1s + l * (16 * H_N);
        const float* b1 = b1s + l * H_N;
        const float* Wh = Whs + l * (H_N * H_N);
        const float* bh = bhs + l * H_N;
        const float* Wo = Wos + l * (H_N * DOUT_N);
        const float* bo = bos + l * DOUT_N;
        const int*   pm = perms + l * D_N;

        // ---- h1 = relu([x1, c] @ W1 + b1) : 16 -> 128
        for (int j = 0; j < H_N; j += 4) {
            float a0 = b1[j+0], a1 = b1[j+1], a2 = b1[j+2], a3 = b1[j+3];
            #pragma unroll
            for (int k = 0; k < 16; ++k) {
                const float ik = (k < 8) ? xr[k] : cr[k - 8];
                const float* w = W1 + k * H_N + j;
                a0 = fmaf(ik, w[0], a0);
                a1 = fmaf(ik, w[1], a1);
                a2 = fmaf(ik, w[2], a2);
                a3 = fmaf(ik, w[3], a3);
            }
            h1s[j+0][t] = (_Float16)fmaxf(a0, 0.f);
            h1s[j+1][t] = (_Float16)fmaxf(a1, 0.f);
            h1s[j+2][t] = (_Float16)fmaxf(a2, 0.f);
            h1s[j+3][t] = (_Float16)fmaxf(a3, 0.f);
        }

        // ---- h2 = relu(h1 @ Wh + bh) : 128 -> 128, output in 4 chunks of 32
        #pragma unroll
        for (int jc = 0; jc < 4; ++jc) {
            float acc[32];
            #pragma unroll
            for (int j = 0; j < 32; ++j) acc[j] = bh[jc*32 + j];
            #pragma unroll 2
            for (int k = 0; k < H_N; ++k) {
                const float hk = (float)h1s[k][t];
                const float* w = Wh + k * H_N + jc * 32;
                #pragma unroll
                for (int j = 0; j < 32; ++j) acc[j] = fmaf(hk, w[j], acc[j]);
            }
            #pragma unroll
            for (int j = 0; j < 32; ++j) h2s[jc*32 + j][t] = (_Float16)fmaxf(acc[j], 0.f);
        }

        // stash current x (x_out = [x1, y2] will be built here)
        #pragma unroll
        for (int j = 0; j < D_N; ++j) xbuf[j][t] = xr[j];

        float lsum = 0.f;
        for (int d = 0; d < 8; ++d) {
            // ---- theta[31] = h2 @ Wo[:, 31d:31d+31] + bo
            float th[31];
            #pragma unroll
            for (int c0 = 0; c0 < 31; ++c0) th[c0] = bo[31*d + c0];
            #pragma unroll 2
            for (int k = 0; k < H_N; ++k) {
                const float hk = (float)h2s[k][t];
                const float* w = Wo + k * DOUT_N + 31*d;
                #pragma unroll
                for (int c0 = 0; c0 < 31; ++c0) th[c0] = fmaf(hk, w[c0], th[c0]);
            }

            // ---- rational-quadratic spline on x2[d]
            const float x2 = xbuf[8 + d][t];

            float bw[10], bhh[10], sl[11];
            // softmax_with_min over th[0..9] -> bin widths
            float m1 = th[0];
            #pragma unroll
            for (int i = 1; i < 10; ++i) m1 = fmaxf(m1, th[i]);
            float se = 0.f;
            #pragma unroll
            for (int i = 0; i < 10; ++i) { bw[i] = expf(th[i] - m1); se += bw[i]; }
            const float inv = 1.f / se;
            #pragma unroll
            for (int i = 0; i < 10; ++i) bw[i] = 2.f * (PMIN_F + 0.99f * bw[i] * inv);

            // softmax_with_min over th[10..19] -> bin heights
            float m2 = th[10];
            #pragma unroll
            for (int i = 1; i < 10; ++i) m2 = fmaxf(m2, th[10+i]);
            float se2 = 0.f;
            #pragma unroll
            for (int i = 0; i < 10; ++i) { bhh[i] = expf(th[10+i] - m2); se2 += bhh[i]; }
            const float inv2 = 1.f / se2;
            #pragma unroll
            for (int i = 0; i < 10; ++i) bhh[i] = 2.f * (PMIN_F + 0.99f * bhh[i] * inv2);

            // slopes = PMIN + (1-PMIN)*softplus(th[20..30])/ln(2)
            #pragma unroll
            for (int i = 0; i < 11; ++i) {
                const float u = th[20 + i];
                const float sp = (u > 0.f) ? (u + log1pf(expf(-u))) : log1pf(expf(u));
                sl[i] = PMIN_F + (1.f - PMIN_F) * sp * 1.44269504088896340736f;
            }

            // bin index: sum(x_knots < x2) - 1, knots = cumsum(bw) - 1 with leading -1
            int cnt = (-1.f < x2) ? 1 : 0;
            float run = -1.f;
            #pragma unroll
            for (int i = 0; i < 10; ++i) { run += bw[i]; cnt += (run < x2) ? 1 : 0; }
            const int bidx = cnt - 1;
            const bool inb = (bidx >= 0) && (bidx < 10);
            const int ci = bidx < 0 ? 0 : (bidx > 9 ? 9 : bidx);

            // gather knot/bin params at ci via select-scan
            float x1k = -1.f, y1k = -1.f, xw = 1.f, yw = 1.f, dd1 = 1.f, dd2 = 1.f;
            float rx = -1.f, ry = -1.f;
            #pragma unroll
            for (int i = 0; i < 10; ++i) {
                const bool pick = (i == ci);
                x1k = pick ? rx      : x1k;
                y1k = pick ? ry      : y1k;
                xw  = pick ? bw[i]   : xw;
                yw  = pick ? bhh[i]  : yw;
                dd1 = pick ? sl[i]   : dd1;
                dd2 = pick ? sl[i+1] : dd2;
                rx += bw[i];
                ry += bhh[i];
            }
            // rx = x_knots[K] (right edge), ry = y_knots[K] (top edge)

            const float xs  = inb ? x2 : (x1k + 0.5f * xw);
            const float s   = yw / xw;
            const float eta = (xs - x1k) / xw;
            const float rev = 1.f - eta;
            const float er  = eta * rev;
            const float dn  = s + (dd1 + dd2 - 2.f*s) * er;
            const float yrq = y1k + yw * (s*eta*eta + dd1*er) / dn;
            const float jn  = s*s*(dd2*eta*eta + 2.f*s*er + dd1*rev*rev);
            const float ljx = logf(jn) - 2.f*logf(dn);
            const float ylin = (ry + 1.f) / (rx + 1.f) * (x2 + 1.f) - 1.f;

            xbuf[8 + d][t] = inb ? yrq : ylin;
            lsum += inb ? ljx : 0.f;
        }
        ljd += lsum;

        // ---- permutation: x <- x_out[perm]
        float nx[D_N];
        #pragma unroll
        for (int j = 0; j < D_N; ++j) nx[j] = xbuf[pm[j]][t];
        #pragma unroll
        for (int j = 0; j < D_N; ++j) xr[j] = nx[j];
    }

    // ---- write outputs: x [B,16] then ljd [B]
    float4* op = (float4*)(out + r * D_N);
    op[0] = make_float4(xr[0],  xr[1],  xr[2],  xr[3]);
    op[1] = make_float4(xr[4],  xr[5],  xr[6],  xr[7]);
    op[2] = make_float4(xr[8],  xr[9],  xr[10], xr[11]);
    op[3] = make_float4(xr[12], xr[13], xr[14], xr[15]);
    out[(long long)B_N * D_N + r] = ljd;
}

extern "C" void kernel_launch(void* const* d_in, const int* in_sizes, int n_in,
                              void* d_out, int out_size, void* d_ws, size_t ws_size,
                              hipStream_t stream) {
    const float* x    = (const float*)d_in[0];
    const float* c    = (const float*)d_in[1];
    const float* W1s  = (const float*)d_in[2];
    const float* b1s  = (const float*)d_in[3];
    const float* Whs  = (const float*)d_in[4];
    const float* bhs  = (const float*)d_in[5];
    const float* Wos  = (const float*)d_in[6];
    const float* bos  = (const float*)d_in[7];
    const int*   perms = (const int*)d_in[8];
    float* out = (float*)d_out;

    dim3 grid(B_N / 64), block(64);
    flow_kernel<<<grid, block, 0, stream>>>(x, c, W1s, b1s, Whs, bhs, Wos, bos, perms, out);
}

// Round 2
// 848.652 us; speedup vs baseline: 9.1476x; 9.1476x over previous
//
#include <hip/hip_runtime.h>

#define B_N   262144
#define PMIN_F 0.001f

typedef _Float16 half8 __attribute__((ext_vector_type(8)));
typedef float    floatx4 __attribute__((ext_vector_type(4)));

// ---------------------------------------------------------------------------
// Prep: convert weights fp32 -> f16 in MFMA B-fragment order into d_ws.
// Fragment for (ntile, kstep): lane (kg=lane>>4, c=lane&15) holds 8 halves
// B[kstep*32 + kg*8 + j][ntile*16 + c],  j=0..7.
// Per layer, 104 fragment blocks of 512 halves:
//   r in [0,8)   : mm1 (W1 16x128, K padded to 32 with zeros), r = ntile
//   r in [8,40)  : mm2 (Wh 128x128), r = 8 + ntile*4 + kstep
//   r in [40,104): mm3 (Wo 128x248, N padded to 256), r = 40 + ntile*4 + kstep
// ---------------------------------------------------------------------------
__global__ __launch_bounds__(64) void prep_kernel(
    const float* __restrict__ W1s, const float* __restrict__ Whs,
    const float* __restrict__ Wos, _Float16* __restrict__ ws)
{
    const int bid   = blockIdx.x;          // 0..415
    const int layer = bid / 104;
    const int r     = bid % 104;
    const int lane  = threadIdx.x;
    const int kg    = lane >> 4;
    const int c     = lane & 15;

    half8 v;
    if (r < 8) {
        const int nt = r, n = nt * 16 + c;
        const float* W1 = W1s + layer * 16 * 128;
        #pragma unroll
        for (int j = 0; j < 8; ++j) {
            const int k = kg * 8 + j;
            v[j] = (k < 16) ? (_Float16)W1[k * 128 + n] : (_Float16)0.f;
        }
    } else if (r < 40) {
        const int f = r - 8, nt = f >> 2, ks = f & 3, n = nt * 16 + c;
        const float* Wh = Whs + layer * 128 * 128;
        #pragma unroll
        for (int j = 0; j < 8; ++j) {
            const int k = ks * 32 + kg * 8 + j;
            v[j] = (_Float16)Wh[k * 128 + n];
        }
    } else {
        const int f = r - 40, nt = f >> 2, ks = f & 3, n = nt * 16 + c;
        const float* Wo = Wos + layer * 128 * 248;
        #pragma unroll
        for (int j = 0; j < 8; ++j) {
            const int k = ks * 32 + kg * 8 + j;
            v[j] = (n < 248) ? (_Float16)Wo[k * 248 + n] : (_Float16)0.f;
        }
    }
    *(half8*)(ws + (size_t)bid * 512 + lane * 8) = v;
}

// ---------------------------------------------------------------------------
// Main kernel: one wave (64 threads) handles 16 rows end-to-end.
// mfma_f32_16x16x32_f16 layouts (gfx950):
//   A: lane holds A[m=lane&15][k=(lane>>4)*8+j]
//   B: lane holds B[k=(lane>>4)*8+j][n=lane&15]
//   C/D: lane holds D[row=(lane>>4)*4+reg][col=lane&15]
// LDS/wave: xls 1KB + cls 256B + R 8KB = 9.25KB -> 16 waves/CU.
// ---------------------------------------------------------------------------
__global__ __launch_bounds__(64, 4) void flow_mfma(
    const float* __restrict__ x_in,
    const float* __restrict__ c_in,
    const float* __restrict__ b1s,
    const float* __restrict__ bhs,
    const float* __restrict__ bos,
    const int*   __restrict__ perms,
    const _Float16* __restrict__ wsW,
    float* __restrict__ out)
{
    __shared__ __align__(16) float    xls[256];    // [16 rows][16]
    __shared__ __align__(16) _Float16 cls[128];    // [16 rows][8]
    __shared__ __align__(16) _Float16 R[4096];     // h1 [0,2048) | h2 [2048,4096); theta overlays [0,3968)

    const int lane = threadIdx.x;
    const int q    = lane >> 4;     // quad (k-group / row-group)
    const int m    = lane & 15;     // col within tile
    const long long row0 = (long long)blockIdx.x * 16;

    // ---- load x (16 rows x 16 f32) and c (16 rows x 8 -> f16)
    {
        const float4 v = ((const float4*)(x_in + row0 * 16))[lane];
        *(float4*)&xls[lane * 4] = v;
        const float2 cv = ((const float2*)(c_in + row0 * 8))[lane];
        cls[lane * 2]     = (_Float16)cv.x;
        cls[lane * 2 + 1] = (_Float16)cv.y;
    }
    __syncthreads();

    float ljd_lo = 0.f, ljd_hi = 0.f;

    for (int l = 0; l < 4; ++l) {
        const _Float16* wsl = wsW + (size_t)l * 104 * 512;
        const float* b1 = b1s + l * 128;
        const float* bh = bhs + l * 128;
        const float* bo = bos + l * 248;

        // ================= mm1: [x1,c] @ W1 -> h1 (16x128) =================
        half8 a1;
        #pragma unroll
        for (int j = 0; j < 8; ++j) a1[j] = (_Float16)0.f;
        if (q == 0) {
            #pragma unroll
            for (int j = 0; j < 8; ++j) a1[j] = (_Float16)xls[m * 16 + j];
        } else if (q == 1) {
            a1 = *(const half8*)&cls[m * 8];
        }

        {
            floatx4 acc[8];
            #pragma unroll
            for (int nt = 0; nt < 8; ++nt) {
                const float bb = b1[nt * 16 + m];
                acc[nt][0] = bb; acc[nt][1] = bb; acc[nt][2] = bb; acc[nt][3] = bb;
                const half8 b = *(const half8*)(wsl + nt * 512 + lane * 8);
                acc[nt] = __builtin_amdgcn_mfma_f32_16x16x32_f16(a1, b, acc[nt], 0, 0, 0);
            }
            // relu + store h1 in A-frag order: elem (row mm, k=n) at
            // ((n>>5)*64 + ((n>>3)&3)*16 + mm)*8 + (n&7)
            #pragma unroll
            for (int nt = 0; nt < 8; ++nt) {
                #pragma unroll
                for (int reg = 0; reg < 4; ++reg) {
                    const float v = fmaxf(acc[nt][reg], 0.f);
                    const int mm = q * 4 + reg;
                    const int n  = nt * 16 + m;
                    R[((n >> 5) * 64 + ((n >> 3) & 3) * 16 + mm) * 8 + (n & 7)] = (_Float16)v;
                }
            }
        }
        __syncthreads();

        // ================= mm2: h1 @ Wh -> h2 (16x128) =====================
        {
            floatx4 acc[8];
            #pragma unroll
            for (int nt = 0; nt < 8; ++nt) {
                const float bb = bh[nt * 16 + m];
                acc[nt][0] = bb; acc[nt][1] = bb; acc[nt][2] = bb; acc[nt][3] = bb;
            }
            #pragma unroll
            for (int ks = 0; ks < 4; ++ks) {
                const half8 a = *(const half8*)&R[(ks * 64 + lane) * 8];
                #pragma unroll
                for (int nt = 0; nt < 8; ++nt) {
                    const half8 b = *(const half8*)(wsl + (8 + nt * 4 + ks) * 512 + lane * 8);
                    acc[nt] = __builtin_amdgcn_mfma_f32_16x16x32_f16(a, b, acc[nt], 0, 0, 0);
                }
            }
            #pragma unroll
            for (int nt = 0; nt < 8; ++nt) {
                #pragma unroll
                for (int reg = 0; reg < 4; ++reg) {
                    const float v = fmaxf(acc[nt][reg], 0.f);
                    const int mm = q * 4 + reg;
                    const int n  = nt * 16 + m;
                    R[2048 + ((n >> 5) * 64 + ((n >> 3) & 3) * 16 + mm) * 8 + (n & 7)] = (_Float16)v;
                }
            }
        }
        __syncthreads();

        // ================= mm3: h2 @ Wo -> theta (16x248) ==================
        half8 a3[4];
        #pragma unroll
        for (int ks = 0; ks < 4; ++ks)
            a3[ks] = *(const half8*)&R[2048 + (ks * 64 + lane) * 8];
        __syncthreads();   // a3 in regs; theta may now overwrite R

        #pragma unroll
        for (int hf = 0; hf < 2; ++hf) {
            floatx4 acc[8];
            #pragma unroll
            for (int nt8 = 0; nt8 < 8; ++nt8) {
                const int n = (hf * 8 + nt8) * 16 + m;
                const float bb = (n < 248) ? bo[n] : 0.f;
                acc[nt8][0] = bb; acc[nt8][1] = bb; acc[nt8][2] = bb; acc[nt8][3] = bb;
            }
            #pragma unroll
            for (int ks = 0; ks < 4; ++ks) {
                #pragma unroll
                for (int nt8 = 0; nt8 < 8; ++nt8) {
                    const int nt = hf * 8 + nt8;
                    const half8 b = *(const half8*)(wsl + (40 + nt * 4 + ks) * 512 + lane * 8);
                    acc[nt8] = __builtin_amdgcn_mfma_f32_16x16x32_f16(a3[ks], b, acc[nt8], 0, 0, 0);
                }
            }
            #pragma unroll
            for (int nt8 = 0; nt8 < 8; ++nt8) {
                #pragma unroll
                for (int reg = 0; reg < 4; ++reg) {
                    const int n  = (hf * 8 + nt8) * 16 + m;
                    const int mm = q * 4 + reg;
                    if (n < 248) R[mm * 248 + n] = (_Float16)acc[nt8][reg];
                }
            }
        }
        __syncthreads();

        // ================= spline: 128 (row,d) items, 2 per lane ===========
        #pragma unroll
        for (int it = 0; it < 2; ++it) {
            const int item = lane + it * 64;
            const int row  = item >> 3;
            const int d    = item & 7;

            float th[31];
            #pragma unroll
            for (int i = 0; i < 31; ++i) th[i] = (float)R[row * 248 + 31 * d + i];
            const float x2 = xls[row * 16 + 8 + d];

            float bw[10], bhh[10], sl[11];
            float m1 = th[0];
            #pragma unroll
            for (int i = 1; i < 10; ++i) m1 = fmaxf(m1, th[i]);
            float se = 0.f;
            #pragma unroll
            for (int i = 0; i < 10; ++i) { bw[i] = expf(th[i] - m1); se += bw[i]; }
            const float inv = 1.f / se;
            #pragma unroll
            for (int i = 0; i < 10; ++i) bw[i] = 2.f * (PMIN_F + 0.99f * bw[i] * inv);

            float m2 = th[10];
            #pragma unroll
            for (int i = 1; i < 10; ++i) m2 = fmaxf(m2, th[10 + i]);
            float se2 = 0.f;
            #pragma unroll
            for (int i = 0; i < 10; ++i) { bhh[i] = expf(th[10 + i] - m2); se2 += bhh[i]; }
            const float inv2 = 1.f / se2;
            #pragma unroll
            for (int i = 0; i < 10; ++i) bhh[i] = 2.f * (PMIN_F + 0.99f * bhh[i] * inv2);

            #pragma unroll
            for (int i = 0; i < 11; ++i) {
                const float u = th[20 + i];
                const float sp = (u > 0.f) ? (u + log1pf(expf(-u))) : log1pf(expf(u));
                sl[i] = PMIN_F + (1.f - PMIN_F) * sp * 1.44269504088896340736f;
            }

            int cnt = (-1.f < x2) ? 1 : 0;
            float run = -1.f;
            #pragma unroll
            for (int i = 0; i < 10; ++i) { run += bw[i]; cnt += (run < x2) ? 1 : 0; }
            const int bidx = cnt - 1;
            const bool inb = (bidx >= 0) && (bidx < 10);
            const int ci = bidx < 0 ? 0 : (bidx > 9 ? 9 : bidx);

            float x1k = -1.f, y1k = -1.f, xw = 1.f, yw = 1.f, dd1 = 1.f, dd2 = 1.f;
            float rx = -1.f, ry = -1.f;
            #pragma unroll
            for (int i = 0; i < 10; ++i) {
                const bool pick = (i == ci);
                x1k = pick ? rx      : x1k;
                y1k = pick ? ry      : y1k;
                xw  = pick ? bw[i]   : xw;
                yw  = pick ? bhh[i]  : yw;
                dd1 = pick ? sl[i]   : dd1;
                dd2 = pick ? sl[i+1] : dd2;
                rx += bw[i];
                ry += bhh[i];
            }

            const float xs  = inb ? x2 : (x1k + 0.5f * xw);
            const float s   = yw / xw;
            const float eta = (xs - x1k) / xw;
            const float rev = 1.f - eta;
            const float er  = eta * rev;
            const float dn  = s + (dd1 + dd2 - 2.f * s) * er;
            const float yrq = y1k + yw * (s * eta * eta + dd1 * er) / dn;
            const float jn  = s * s * (dd2 * eta * eta + 2.f * s * er + dd1 * rev * rev);
            const float ljx = logf(jn) - 2.f * logf(dn);
            const float ylin = (ry + 1.f) / (rx + 1.f) * (x2 + 1.f) - 1.f;

            xls[row * 16 + 8 + d] = inb ? yrq : ylin;

            float lj = inb ? ljx : 0.f;
            lj += __shfl_xor(lj, 1);
            lj += __shfl_xor(lj, 2);
            lj += __shfl_xor(lj, 4);
            if (it == 0) ljd_lo += lj; else ljd_hi += lj;
        }
        __syncthreads();

        // ================= permutation: x <- x_out[perm] ===================
        {
            const int4 pv = ((const int4*)(perms + l * 16))[lane & 3];
            const int mm = lane >> 2;
            float nv0 = xls[mm * 16 + pv.x];
            float nv1 = xls[mm * 16 + pv.y];
            float nv2 = xls[mm * 16 + pv.z];
            float nv3 = xls[mm * 16 + pv.w];
            __syncthreads();
            *(float4*)&xls[lane * 4] = make_float4(nv0, nv1, nv2, nv3);
        }
        __syncthreads();
    }

    // ---- outputs: x [B,16] then ljd [B]
    {
        const float4 vo = *(const float4*)&xls[lane * 4];
        ((float4*)(out + row0 * 16))[lane] = vo;
    }
    {
        const float a = __shfl(ljd_lo, (lane & 7) * 8);
        const float b = __shfl(ljd_hi, (lane & 7) * 8);
        if (lane < 16)
            out[(size_t)B_N * 16 + row0 + lane] = (lane < 8) ? a : b;
    }
}

extern "C" void kernel_launch(void* const* d_in, const int* in_sizes, int n_in,
                              void* d_out, int out_size, void* d_ws, size_t ws_size,
                              hipStream_t stream) {
    const float* x     = (const float*)d_in[0];
    const float* c     = (const float*)d_in[1];
    const float* W1s   = (const float*)d_in[2];
    const float* b1s   = (const float*)d_in[3];
    const float* Whs   = (const float*)d_in[4];
    const float* bhs   = (const float*)d_in[5];
    const float* Wos   = (const float*)d_in[6];
    const float* bos   = (const float*)d_in[7];
    const int*   perms = (const int*)d_in[8];
    float* out = (float*)d_out;
    _Float16* ws = (_Float16*)d_ws;

    prep_kernel<<<dim3(416), dim3(64), 0, stream>>>(W1s, Whs, Wos, ws);
    flow_mfma<<<dim3(B_N / 16), dim3(64), 0, stream>>>(
        x, c, b1s, bhs, bos, perms, ws, out);
}

// Round 4
// 439.097 us; speedup vs baseline: 17.6797x; 1.9327x over previous
//
#include <hip/hip_runtime.h>

#define B_N   262144
#define PMIN_F 0.001f
#define LOG2E 1.44269504088896340736f
#define LN2   0.69314718055994530942f

typedef _Float16 half4v __attribute__((ext_vector_type(4)));
typedef _Float16 half8  __attribute__((ext_vector_type(8)));
typedef float    floatx4 __attribute__((ext_vector_type(4)));

__device__ __forceinline__ float fexp2(float x) { return __builtin_amdgcn_exp2f(x); }
__device__ __forceinline__ float flog2(float x) { return __builtin_amdgcn_logf(x); }
__device__ __forceinline__ float frcp (float x) { return __builtin_amdgcn_rcpf(x); }

// ---------------------------------------------------------------------------
// Prep: weights fp32 -> f16 in MFMA B-fragment order.
// Fragment (ntile, kstep): lane (kg=lane>>4, c=lane&15) holds 8 halves
// B[kstep*32 + kg*8 + j][ntile*16 + c], j=0..7.
// Per layer 104 blocks of 512 halves:
//   r in [0,8)   : mm1 W1 16x128 (K padded to 32)
//   r in [8,40)  : mm2 Wh 128x128
//   r in [40,104): mm3 Wo 128x248 -> column-remapped to 256 (each d's 31
//                  params padded to a 32-slot). Theta lands in LDS already
//                  padded per spline item.
// ---------------------------------------------------------------------------
__global__ __launch_bounds__(64) void prep_kernel(
    const float* __restrict__ W1s, const float* __restrict__ Whs,
    const float* __restrict__ Wos, _Float16* __restrict__ ws)
{
    const int bid   = blockIdx.x;          // 0..415
    const int layer = bid / 104;
    const int r     = bid % 104;
    const int lane  = threadIdx.x;
    const int kg    = lane >> 4;
    const int c     = lane & 15;

    half8 v;
    if (r < 8) {
        const int nt = r, n = nt * 16 + c;
        const float* W1 = W1s + layer * 16 * 128;
        #pragma unroll
        for (int j = 0; j < 8; ++j) {
            const int k = kg * 8 + j;
            v[j] = (k < 16) ? (_Float16)W1[k * 128 + n] : (_Float16)0.f;
        }
    } else if (r < 40) {
        const int f = r - 8, nt = f >> 2, ks = f & 3, n = nt * 16 + c;
        const float* Wh = Whs + layer * 128 * 128;
        #pragma unroll
        for (int j = 0; j < 8; ++j) {
            const int k = ks * 32 + kg * 8 + j;
            v[j] = (_Float16)Wh[k * 128 + n];
        }
    } else {
        const int f = r - 40, nt = f >> 2, ks = f & 3, n = nt * 16 + c;
        const int dd = n >> 5, cc = n & 31;
        const float* Wo = Wos + layer * 128 * 248;
        #pragma unroll
        for (int j = 0; j < 8; ++j) {
            const int k = ks * 32 + kg * 8 + j;
            v[j] = (cc < 31) ? (_Float16)Wo[k * 248 + dd * 31 + cc] : (_Float16)0.f;
        }
    }
    *(half8*)(ws + (size_t)bid * 512 + lane * 8) = v;
}

// ---------------------------------------------------------------------------
// Main: one wave = 16 rows end-to-end.
// mfma_f32_16x16x32_f16: A lane holds A[m=lane&15][k=q*8+j];
// C/D lane holds D[row=q*4+reg][col=lane&15].
// LDS: h1/h2 row-major stride 132 halves (conflict-free C-stores, b64 A-reads);
// theta overlay stride 260 halves, 32-padded per spline item.
// ---------------------------------------------------------------------------
__global__ __launch_bounds__(64) void flow_mfma(
    const float* __restrict__ x_in,
    const float* __restrict__ c_in,
    const float* __restrict__ b1s,
    const float* __restrict__ bhs,
    const float* __restrict__ bos,
    const int*   __restrict__ perms,
    const _Float16* __restrict__ wsW,
    float* __restrict__ out)
{
    __shared__ __align__(16) float    xls[256];    // [16 rows][16]
    __shared__ __align__(16) _Float16 cls[128];    // [16 rows][8]
    // h1 at [0,2112), h2 at [2112,4224); theta overlays [0,4160) stride 260
    __shared__ __align__(16) _Float16 R[4224];

    const int lane = threadIdx.x;
    const int q    = lane >> 4;
    const int m    = lane & 15;
    const long long row0 = (long long)blockIdx.x * 16;

    {
        const float4 v = ((const float4*)(x_in + row0 * 16))[lane];
        *(float4*)&xls[lane * 4] = v;
        const float2 cv = ((const float2*)(c_in + row0 * 8))[lane];
        cls[lane * 2]     = (_Float16)cv.x;
        cls[lane * 2 + 1] = (_Float16)cv.y;
    }
    __syncthreads();

    float ljd_lo = 0.f, ljd_hi = 0.f;

    for (int l = 0; l < 4; ++l) {
        const _Float16* wsl = wsW + (size_t)l * 104 * 512;
        const float* b1 = b1s + l * 128;
        const float* bh = bhs + l * 128;
        const float* bo = bos + l * 248;

        // ================= mm1: [x1,c] @ W1 -> h1 =================
        half8 a1;
        #pragma unroll
        for (int j = 0; j < 8; ++j) a1[j] = (_Float16)0.f;
        if (q == 0) {
            #pragma unroll
            for (int j = 0; j < 8; ++j) a1[j] = (_Float16)xls[m * 16 + j];
        } else if (q == 1) {
            a1 = *(const half8*)&cls[m * 8];
        }
        {
            floatx4 acc[8];
            #pragma unroll
            for (int nt = 0; nt < 8; ++nt) {
                const float bb = b1[nt * 16 + m];
                acc[nt][0] = bb; acc[nt][1] = bb; acc[nt][2] = bb; acc[nt][3] = bb;
                const half8 b = *(const half8*)(wsl + nt * 512 + lane * 8);
                acc[nt] = __builtin_amdgcn_mfma_f32_16x16x32_f16(a1, b, acc[nt], 0, 0, 0);
            }
            #pragma unroll
            for (int nt = 0; nt < 8; ++nt)
                #pragma unroll
                for (int reg = 0; reg < 4; ++reg)
                    R[(q * 4 + reg) * 132 + nt * 16 + m] =
                        (_Float16)fmaxf(acc[nt][reg], 0.f);
        }
        __syncthreads();

        // ================= mm2: h1 @ Wh -> h2 =================
        {
            floatx4 acc[8];
            #pragma unroll
            for (int nt = 0; nt < 8; ++nt) {
                const float bb = bh[nt * 16 + m];
                acc[nt][0] = bb; acc[nt][1] = bb; acc[nt][2] = bb; acc[nt][3] = bb;
            }
            #pragma unroll
            for (int ks = 0; ks < 4; ++ks) {
                const half4v lo = *(const half4v*)&R[m * 132 + ks * 32 + q * 8];
                const half4v hi = *(const half4v*)&R[m * 132 + ks * 32 + q * 8 + 4];
                const half8 a = __builtin_shufflevector(lo, hi, 0, 1, 2, 3, 4, 5, 6, 7);
                #pragma unroll
                for (int nt = 0; nt < 8; ++nt) {
                    const half8 b = *(const half8*)(wsl + (8 + nt * 4 + ks) * 512 + lane * 8);
                    acc[nt] = __builtin_amdgcn_mfma_f32_16x16x32_f16(a, b, acc[nt], 0, 0, 0);
                }
            }
            #pragma unroll
            for (int nt = 0; nt < 8; ++nt)
                #pragma unroll
                for (int reg = 0; reg < 4; ++reg)
                    R[2112 + (q * 4 + reg) * 132 + nt * 16 + m] =
                        (_Float16)fmaxf(acc[nt][reg], 0.f);
        }
        __syncthreads();

        // ================= mm3: h2 @ Wo' -> theta (16x256 padded) =========
        half8 a3[4];
        #pragma unroll
        for (int ks = 0; ks < 4; ++ks) {
            const half4v lo = *(const half4v*)&R[2112 + m * 132 + ks * 32 + q * 8];
            const half4v hi = *(const half4v*)&R[2112 + m * 132 + ks * 32 + q * 8 + 4];
            a3[ks] = __builtin_shufflevector(lo, hi, 0, 1, 2, 3, 4, 5, 6, 7);
        }
        __syncthreads();   // a3 in regs; theta may overwrite R

        #pragma unroll
        for (int hf = 0; hf < 2; ++hf) {
            floatx4 acc[8];
            #pragma unroll
            for (int nt8 = 0; nt8 < 8; ++nt8) {
                const int nt = hf * 8 + nt8;
                const float bb = ((nt & 1) && m == 15) ? 0.f
                               : bo[(nt >> 1) * 31 + (nt & 1) * 16 + m];
                acc[nt8][0] = bb; acc[nt8][1] = bb; acc[nt8][2] = bb; acc[nt8][3] = bb;
            }
            #pragma unroll
            for (int ks = 0; ks < 4; ++ks) {
                #pragma unroll
                for (int nt8 = 0; nt8 < 8; ++nt8) {
                    const int nt = hf * 8 + nt8;
                    const half8 b = *(const half8*)(wsl + (40 + nt * 4 + ks) * 512 + lane * 8);
                    acc[nt8] = __builtin_amdgcn_mfma_f32_16x16x32_f16(a3[ks], b, acc[nt8], 0, 0, 0);
                }
            }
            #pragma unroll
            for (int nt8 = 0; nt8 < 8; ++nt8)
                #pragma unroll
                for (int reg = 0; reg < 4; ++reg)
                    R[(q * 4 + reg) * 260 + (hf * 8 + nt8) * 16 + m] =
                        (_Float16)acc[nt8][reg];
        }
        __syncthreads();

        // ================= spline: 128 items, 2/lane =================
        #pragma unroll
        for (int it = 0; it < 2; ++it) {
            const int item = lane + it * 64;
            const int row  = item >> 3;
            const int d    = item & 7;
            const int base = row * 260 + d * 32;

            float th[31];
            #pragma unroll
            for (int j = 0; j < 8; ++j) {
                const half4v v = *(const half4v*)&R[base + j * 4];
                #pragma unroll
                for (int e = 0; e < 4; ++e) {
                    const int idx = j * 4 + e;
                    if (idx < 31) th[idx] = (float)v[e];
                }
            }
            const float x2 = xls[row * 16 + 8 + d];

            float bw[10], bhh[10], sl[11];
            float m1 = th[0];
            #pragma unroll
            for (int i = 1; i < 10; ++i) m1 = fmaxf(m1, th[i]);
            float se = 0.f;
            #pragma unroll
            for (int i = 0; i < 10; ++i) { bw[i] = fexp2((th[i] - m1) * LOG2E); se += bw[i]; }
            const float inv = frcp(se);
            // coefficient is (1 - PMIN*K) = 0.99 for widths/heights (NOT 0.999)
            #pragma unroll
            for (int i = 0; i < 10; ++i) bw[i] = 2.f * (PMIN_F + 0.99f * bw[i] * inv);

            float m2 = th[10];
            #pragma unroll
            for (int i = 1; i < 10; ++i) m2 = fmaxf(m2, th[10 + i]);
            float se2 = 0.f;
            #pragma unroll
            for (int i = 0; i < 10; ++i) { bhh[i] = fexp2((th[10 + i] - m2) * LOG2E); se2 += bhh[i]; }
            const float inv2 = frcp(se2);
            #pragma unroll
            for (int i = 0; i < 10; ++i) bhh[i] = 2.f * (PMIN_F + 0.99f * bhh[i] * inv2);

            // slopes: coefficient is (1 - PMIN) = 0.999
            #pragma unroll
            for (int i = 0; i < 11; ++i) {
                const float t = th[20 + i] * LOG2E;
                const float sp2 = (t > 15.f) ? t : flog2(1.f + fexp2(t));
                sl[i] = PMIN_F + 0.999f * sp2;
            }

            int cnt = (-1.f < x2) ? 1 : 0;
            float run = -1.f;
            #pragma unroll
            for (int i = 0; i < 10; ++i) { run += bw[i]; cnt += (run < x2) ? 1 : 0; }
            const int bidx = cnt - 1;
            const bool inb = (bidx >= 0) && (bidx < 10);
            const int ci = bidx < 0 ? 0 : (bidx > 9 ? 9 : bidx);

            float x1k = -1.f, y1k = -1.f, xw = 1.f, yw = 1.f, dd1 = 1.f, dd2 = 1.f;
            float rx = -1.f, ry = -1.f;
            #pragma unroll
            for (int i = 0; i < 10; ++i) {
                const bool pick = (i == ci);
                x1k = pick ? rx      : x1k;
                y1k = pick ? ry      : y1k;
                xw  = pick ? bw[i]   : xw;
                yw  = pick ? bhh[i]  : yw;
                dd1 = pick ? sl[i]   : dd1;
                dd2 = pick ? sl[i+1] : dd2;
                rx += bw[i];
                ry += bhh[i];
            }

            const float xs  = inb ? x2 : (x1k + 0.5f * xw);
            const float rxw = frcp(xw);
            const float s   = yw * rxw;
            const float eta = (xs - x1k) * rxw;
            const float rev = 1.f - eta;
            const float er  = eta * rev;
            const float dn  = s + (dd1 + dd2 - 2.f * s) * er;
            const float yrq = y1k + yw * (s * eta * eta + dd1 * er) * frcp(dn);
            const float jn  = s * s * (dd2 * eta * eta + 2.f * s * er + dd1 * rev * rev);
            const float ljx = LN2 * (flog2(jn) - 2.f * flog2(dn));
            const float ylin = (ry + 1.f) * frcp(rx + 1.f) * (x2 + 1.f) - 1.f;

            xls[row * 16 + 8 + d] = inb ? yrq : ylin;

            float lj = inb ? ljx : 0.f;
            lj += __shfl_xor(lj, 1);
            lj += __shfl_xor(lj, 2);
            lj += __shfl_xor(lj, 4);
            if (it == 0) ljd_lo += lj; else ljd_hi += lj;
        }
        __syncthreads();

        // ================= permutation =================
        {
            const int4 pv = ((const int4*)(perms + l * 16))[lane & 3];
            const int mm = lane >> 2;
            float nv0 = xls[mm * 16 + pv.x];
            float nv1 = xls[mm * 16 + pv.y];
            float nv2 = xls[mm * 16 + pv.z];
            float nv3 = xls[mm * 16 + pv.w];
            __syncthreads();
            *(float4*)&xls[lane * 4] = make_float4(nv0, nv1, nv2, nv3);
        }
        __syncthreads();
    }

    {
        const float4 vo = *(const float4*)&xls[lane * 4];
        ((float4*)(out + row0 * 16))[lane] = vo;
    }
    {
        const float a = __shfl(ljd_lo, (lane & 7) * 8);
        const float b = __shfl(ljd_hi, (lane & 7) * 8);
        if (lane < 16)
            out[(size_t)B_N * 16 + row0 + lane] = (lane < 8) ? a : b;
    }
}

extern "C" void kernel_launch(void* const* d_in, const int* in_sizes, int n_in,
                              void* d_out, int out_size, void* d_ws, size_t ws_size,
                              hipStream_t stream) {
    const float* x     = (const float*)d_in[0];
    const float* c     = (const float*)d_in[1];
    const float* W1s   = (const float*)d_in[2];
    const float* b1s   = (const float*)d_in[3];
    const float* Whs   = (const float*)d_in[4];
    const float* bhs   = (const float*)d_in[5];
    const float* Wos   = (const float*)d_in[6];
    const float* bos   = (const float*)d_in[7];
    const int*   perms = (const int*)d_in[8];
    float* out = (float*)d_out;
    _Float16* ws = (_Float16*)d_ws;

    prep_kernel<<<dim3(416), dim3(64), 0, stream>>>(W1s, Whs, Wos, ws);
    flow_mfma<<<dim3(B_N / 16), dim3(64), 0, stream>>>(
        x, c, b1s, bhs, bos, perms, ws, out);
}

// Round 5
// 318.240 us; speedup vs baseline: 24.3938x; 1.3798x over previous
//
#include <hip/hip_runtime.h>

#define B_N   262144
#define PMIN_F 0.001f
#define LOG2E 1.44269504088896340736f
#define LN2   0.69314718055994530942f

typedef _Float16 half4v __attribute__((ext_vector_type(4)));
typedef _Float16 half8  __attribute__((ext_vector_type(8)));
typedef float    floatx4 __attribute__((ext_vector_type(4)));

__device__ __forceinline__ float fexp2(float x) { return __builtin_amdgcn_exp2f(x); }
__device__ __forceinline__ float flog2(float x) { return __builtin_amdgcn_logf(x); }
__device__ __forceinline__ float frcp (float x) { return __builtin_amdgcn_rcpf(x); }

// ---------------------------------------------------------------------------
// Prep: weights fp32 -> f16 in MFMA B-fragment order.
// Fragment (ntile, kstep): lane (kg=lane>>4, c=lane&15) holds 8 halves
// B[kstep*32 + kg*8 + j][ntile*16 + c], j=0..7.
// Per layer 104 blocks of 512 halves:
//   r in [0,8)   : mm1 W1 16x128, K padded to 32; row k==16 carries b1
//                  (bias-in-K: A provides 1.0 at k=16)
//   r in [8,40)  : mm2 Wh 128x128
//   r in [40,104): mm3 Wo 128x248 column-remapped to 256 (31->32 pad per d)
// ---------------------------------------------------------------------------
__global__ __launch_bounds__(64) void prep_kernel(
    const float* __restrict__ W1s, const float* __restrict__ b1s,
    const float* __restrict__ Whs, const float* __restrict__ Wos,
    _Float16* __restrict__ ws)
{
    const int bid   = blockIdx.x;          // 0..415
    const int layer = bid / 104;
    const int r     = bid % 104;
    const int lane  = threadIdx.x;
    const int kg    = lane >> 4;
    const int c     = lane & 15;

    half8 v;
    if (r < 8) {
        const int nt = r, n = nt * 16 + c;
        const float* W1 = W1s + layer * 16 * 128;
        const float* b1 = b1s + layer * 128;
        #pragma unroll
        for (int j = 0; j < 8; ++j) {
            const int k = kg * 8 + j;
            v[j] = (k < 16) ? (_Float16)W1[k * 128 + n]
                 : (k == 16) ? (_Float16)b1[n] : (_Float16)0.f;
        }
    } else if (r < 40) {
        const int f = r - 8, nt = f >> 2, ks = f & 3, n = nt * 16 + c;
        const float* Wh = Whs + layer * 128 * 128;
        #pragma unroll
        for (int j = 0; j < 8; ++j) {
            const int k = ks * 32 + kg * 8 + j;
            v[j] = (_Float16)Wh[k * 128 + n];
        }
    } else {
        const int f = r - 40, nt = f >> 2, ks = f & 3, n = nt * 16 + c;
        const int dd = n >> 5, cc = n & 31;
        const float* Wo = Wos + layer * 128 * 248;
        #pragma unroll
        for (int j = 0; j < 8; ++j) {
            const int k = ks * 32 + kg * 8 + j;
            v[j] = (cc < 31) ? (_Float16)Wo[k * 248 + dd * 31 + cc] : (_Float16)0.f;
        }
    }
    *(half8*)(ws + (size_t)bid * 512 + lane * 8) = v;
}

// ---------------------------------------------------------------------------
// Main: one wave = 32 rows (2 independent 16-row tiles). Each B-fragment
// load feeds 2 MFMAs (halves L2 weight traffic, doubles MFMA ILP).
// mfma_f32_16x16x32_f16: A lane holds A[m=lane&15][k=q*8+j];
// C/D lane holds D[row=q*4+reg][col=lane&15].
// LDS/WG: 2*(1KB xls + 256B cls + 8.25KB R) = 19.4 KB -> 8 WGs/CU.
// ---------------------------------------------------------------------------
__global__ __launch_bounds__(64) void flow_mfma(
    const float* __restrict__ x_in,
    const float* __restrict__ c_in,
    const float* __restrict__ bhs,
    const float* __restrict__ bos,
    const int*   __restrict__ perms,
    const _Float16* __restrict__ wsW,
    float* __restrict__ out)
{
    __shared__ __align__(16) float    xls[2][256];   // [tile][16 rows][16]
    __shared__ __align__(16) _Float16 cls[2][128];   // [tile][16 rows][8]
    // per tile: h1 [0,2112), h2 [2112,4224); theta overlays [0,4160) stride 260
    __shared__ __align__(16) _Float16 R[2][4224];

    const int lane = threadIdx.x;
    const int q    = lane >> 4;
    const int m    = lane & 15;
    const long long row0 = (long long)blockIdx.x * 32;

    {
        const float4* xp = (const float4*)(x_in + row0 * 16);
        *(float4*)&xls[0][lane * 4] = xp[lane];
        *(float4*)&xls[1][lane * 4] = xp[lane + 64];
        const float2* cp = (const float2*)(c_in + row0 * 8);
        const float2 c0 = cp[lane], c1 = cp[lane + 64];
        cls[0][lane * 2]     = (_Float16)c0.x;
        cls[0][lane * 2 + 1] = (_Float16)c0.y;
        cls[1][lane * 2]     = (_Float16)c1.x;
        cls[1][lane * 2 + 1] = (_Float16)c1.y;
    }
    __syncthreads();

    float ljacc[4] = {0.f, 0.f, 0.f, 0.f};   // [tile*2 + half]

    for (int l = 0; l < 4; ++l) {
        const _Float16* wsl = wsW + (size_t)l * 104 * 512;
        const float* bh = bhs + l * 128;
        const float* bo = bos + l * 248;

        // ================= mm1: [x1,c,1] @ [W1;b1] -> h1 =================
        half8 a1[2];
        #pragma unroll
        for (int t2 = 0; t2 < 2; ++t2) {
            #pragma unroll
            for (int j = 0; j < 8; ++j) a1[t2][j] = (_Float16)0.f;
            if (q == 0) {
                const float4 lo = *(const float4*)&xls[t2][m * 16];
                const float4 hi = *(const float4*)&xls[t2][m * 16 + 4];
                a1[t2][0] = (_Float16)lo.x; a1[t2][1] = (_Float16)lo.y;
                a1[t2][2] = (_Float16)lo.z; a1[t2][3] = (_Float16)lo.w;
                a1[t2][4] = (_Float16)hi.x; a1[t2][5] = (_Float16)hi.y;
                a1[t2][6] = (_Float16)hi.z; a1[t2][7] = (_Float16)hi.w;
            } else if (q == 1) {
                a1[t2] = *(const half8*)&cls[t2][m * 8];
            } else if (q == 2) {
                a1[t2][0] = (_Float16)1.f;   // k=16 -> bias row
            }
        }
        {
            const floatx4 z = {0.f, 0.f, 0.f, 0.f};
            floatx4 acc0[8], acc1[8];
            #pragma unroll
            for (int nt = 0; nt < 8; ++nt) {
                const half8 b = *(const half8*)(wsl + nt * 512 + lane * 8);
                acc0[nt] = __builtin_amdgcn_mfma_f32_16x16x32_f16(a1[0], b, z, 0, 0, 0);
                acc1[nt] = __builtin_amdgcn_mfma_f32_16x16x32_f16(a1[1], b, z, 0, 0, 0);
            }
            #pragma unroll
            for (int nt = 0; nt < 8; ++nt)
                #pragma unroll
                for (int reg = 0; reg < 4; ++reg) {
                    R[0][(q * 4 + reg) * 132 + nt * 16 + m] = (_Float16)fmaxf(acc0[nt][reg], 0.f);
                    R[1][(q * 4 + reg) * 132 + nt * 16 + m] = (_Float16)fmaxf(acc1[nt][reg], 0.f);
                }
        }
        __syncthreads();

        // ================= mm2: h1 @ Wh -> h2 =================
        {
            floatx4 acc0[8], acc1[8];
            #pragma unroll
            for (int nt = 0; nt < 8; ++nt) {
                const float bb = bh[nt * 16 + m];
                acc0[nt][0] = bb; acc0[nt][1] = bb; acc0[nt][2] = bb; acc0[nt][3] = bb;
                acc1[nt] = acc0[nt];
            }
            #pragma unroll
            for (int ks = 0; ks < 4; ++ks) {
                half8 a[2];
                #pragma unroll
                for (int t2 = 0; t2 < 2; ++t2) {
                    const half4v lo = *(const half4v*)&R[t2][m * 132 + ks * 32 + q * 8];
                    const half4v hi = *(const half4v*)&R[t2][m * 132 + ks * 32 + q * 8 + 4];
                    a[t2] = __builtin_shufflevector(lo, hi, 0, 1, 2, 3, 4, 5, 6, 7);
                }
                #pragma unroll
                for (int nt = 0; nt < 8; ++nt) {
                    const half8 b = *(const half8*)(wsl + (8 + nt * 4 + ks) * 512 + lane * 8);
                    acc0[nt] = __builtin_amdgcn_mfma_f32_16x16x32_f16(a[0], b, acc0[nt], 0, 0, 0);
                    acc1[nt] = __builtin_amdgcn_mfma_f32_16x16x32_f16(a[1], b, acc1[nt], 0, 0, 0);
                }
            }
            #pragma unroll
            for (int nt = 0; nt < 8; ++nt)
                #pragma unroll
                for (int reg = 0; reg < 4; ++reg) {
                    R[0][2112 + (q * 4 + reg) * 132 + nt * 16 + m] = (_Float16)fmaxf(acc0[nt][reg], 0.f);
                    R[1][2112 + (q * 4 + reg) * 132 + nt * 16 + m] = (_Float16)fmaxf(acc1[nt][reg], 0.f);
                }
        }
        __syncthreads();

        // ================= mm3: h2 @ Wo' -> theta (16x256 padded) =========
        half8 a3[2][4];
        #pragma unroll
        for (int t2 = 0; t2 < 2; ++t2)
            #pragma unroll
            for (int ks = 0; ks < 4; ++ks) {
                const half4v lo = *(const half4v*)&R[t2][2112 + m * 132 + ks * 32 + q * 8];
                const half4v hi = *(const half4v*)&R[t2][2112 + m * 132 + ks * 32 + q * 8 + 4];
                a3[t2][ks] = __builtin_shufflevector(lo, hi, 0, 1, 2, 3, 4, 5, 6, 7);
            }
        __syncthreads();   // a3 in regs; theta may overwrite R

        #pragma unroll
        for (int hf = 0; hf < 2; ++hf) {
            floatx4 acc0[8], acc1[8];
            #pragma unroll
            for (int nt8 = 0; nt8 < 8; ++nt8) {
                const int nt = hf * 8 + nt8;
                const float bb = ((nt & 1) && m == 15) ? 0.f
                               : bo[(nt >> 1) * 31 + (nt & 1) * 16 + m];
                acc0[nt8][0] = bb; acc0[nt8][1] = bb; acc0[nt8][2] = bb; acc0[nt8][3] = bb;
                acc1[nt8] = acc0[nt8];
            }
            #pragma unroll
            for (int ks = 0; ks < 4; ++ks) {
                #pragma unroll
                for (int nt8 = 0; nt8 < 8; ++nt8) {
                    const int nt = hf * 8 + nt8;
                    const half8 b = *(const half8*)(wsl + (40 + nt * 4 + ks) * 512 + lane * 8);
                    acc0[nt8] = __builtin_amdgcn_mfma_f32_16x16x32_f16(a3[0][ks], b, acc0[nt8], 0, 0, 0);
                    acc1[nt8] = __builtin_amdgcn_mfma_f32_16x16x32_f16(a3[1][ks], b, acc1[nt8], 0, 0, 0);
                }
            }
            #pragma unroll
            for (int nt8 = 0; nt8 < 8; ++nt8)
                #pragma unroll
                for (int reg = 0; reg < 4; ++reg) {
                    R[0][(q * 4 + reg) * 260 + (hf * 8 + nt8) * 16 + m] = (_Float16)acc0[nt8][reg];
                    R[1][(q * 4 + reg) * 260 + (hf * 8 + nt8) * 16 + m] = (_Float16)acc1[nt8][reg];
                }
        }
        __syncthreads();

        // ================= spline: 256 items, 4/lane =================
        #pragma unroll
        for (int it = 0; it < 4; ++it) {
            const int t2   = it >> 1;
            const int item = lane + (it & 1) * 64;
            const int row  = item >> 3;
            const int d    = item & 7;
            const int base = row * 260 + d * 32;

            float th[31];
            #pragma unroll
            for (int j = 0; j < 8; ++j) {
                const half4v v = *(const half4v*)&R[t2][base + j * 4];
                #pragma unroll
                for (int e = 0; e < 4; ++e) {
                    const int idx = j * 4 + e;
                    if (idx < 31) th[idx] = (float)v[e];
                }
            }
            const float x2 = xls[t2][row * 16 + 8 + d];

            float bw[10], bhh[10];
            float m1 = th[0];
            #pragma unroll
            for (int i = 1; i < 10; ++i) m1 = fmaxf(m1, th[i]);
            float se = 0.f;
            #pragma unroll
            for (int i = 0; i < 10; ++i) { bw[i] = fexp2((th[i] - m1) * LOG2E); se += bw[i]; }
            const float inv = frcp(se);
            // coefficient (1 - PMIN*K) = 0.99 for widths/heights
            #pragma unroll
            for (int i = 0; i < 10; ++i) bw[i] = 2.f * (PMIN_F + 0.99f * bw[i] * inv);

            float m2 = th[10];
            #pragma unroll
            for (int i = 1; i < 10; ++i) m2 = fmaxf(m2, th[10 + i]);
            float se2 = 0.f;
            #pragma unroll
            for (int i = 0; i < 10; ++i) { bhh[i] = fexp2((th[10 + i] - m2) * LOG2E); se2 += bhh[i]; }
            const float inv2 = frcp(se2);
            #pragma unroll
            for (int i = 0; i < 10; ++i) bhh[i] = 2.f * (PMIN_F + 0.99f * bhh[i] * inv2);

            int cnt = (-1.f < x2) ? 1 : 0;
            float run = -1.f;
            #pragma unroll
            for (int i = 0; i < 10; ++i) { run += bw[i]; cnt += (run < x2) ? 1 : 0; }
            const int bidx = cnt - 1;
            const bool inb = (bidx >= 0) && (bidx < 10);
            const int ci = bidx < 0 ? 0 : (bidx > 9 ? 9 : bidx);

            // select-scan; slopes softplus applied only to the 2 picked knots
            float x1k = -1.f, y1k = -1.f, xw = 1.f, yw = 1.f, u1 = 0.f, u2 = 0.f;
            float rx = -1.f, ry = -1.f;
            #pragma unroll
            for (int i = 0; i < 10; ++i) {
                const bool pick = (i == ci);
                x1k = pick ? rx        : x1k;
                y1k = pick ? ry        : y1k;
                xw  = pick ? bw[i]     : xw;
                yw  = pick ? bhh[i]    : yw;
                u1  = pick ? th[20+i]  : u1;
                u2  = pick ? th[21+i]  : u2;
                rx += bw[i];
                ry += bhh[i];
            }
            const float t1 = u1 * LOG2E;
            const float t2s = u2 * LOG2E;
            const float dd1 = PMIN_F + 0.999f * ((t1  > 15.f) ? t1  : flog2(1.f + fexp2(t1)));
            const float dd2 = PMIN_F + 0.999f * ((t2s > 15.f) ? t2s : flog2(1.f + fexp2(t2s)));

            const float xs  = inb ? x2 : (x1k + 0.5f * xw);
            const float rxw = frcp(xw);
            const float s   = yw * rxw;
            const float eta = (xs - x1k) * rxw;
            const float rev = 1.f - eta;
            const float er  = eta * rev;
            const float dn  = s + (dd1 + dd2 - 2.f * s) * er;
            const float yrq = y1k + yw * (s * eta * eta + dd1 * er) * frcp(dn);
            const float jn  = s * s * (dd2 * eta * eta + 2.f * s * er + dd1 * rev * rev);
            const float ljx = LN2 * (flog2(jn) - 2.f * flog2(dn));
            const float ylin = (ry + 1.f) * frcp(rx + 1.f) * (x2 + 1.f) - 1.f;

            xls[t2][row * 16 + 8 + d] = inb ? yrq : ylin;

            float lj = inb ? ljx : 0.f;
            lj += __shfl_xor(lj, 1);
            lj += __shfl_xor(lj, 2);
            lj += __shfl_xor(lj, 4);
            ljacc[it] += lj;
        }
        __syncthreads();

        // ================= permutation =================
        {
            const int4 pv = ((const int4*)(perms + l * 16))[lane & 3];
            const int mm = lane >> 2;
            const float a0 = xls[0][mm * 16 + pv.x];
            const float a1v = xls[0][mm * 16 + pv.y];
            const float a2 = xls[0][mm * 16 + pv.z];
            const float a3v = xls[0][mm * 16 + pv.w];
            const float b0 = xls[1][mm * 16 + pv.x];
            const float b1v = xls[1][mm * 16 + pv.y];
            const float b2 = xls[1][mm * 16 + pv.z];
            const float b3 = xls[1][mm * 16 + pv.w];
            __syncthreads();
            *(float4*)&xls[0][lane * 4] = make_float4(a0, a1v, a2, a3v);
            *(float4*)&xls[1][lane * 4] = make_float4(b0, b1v, b2, b3);
        }
        __syncthreads();
    }

    // ---- outputs: x [B,16] then ljd [B]
    #pragma unroll
    for (int t2 = 0; t2 < 2; ++t2) {
        const float4 vo = *(const float4*)&xls[t2][lane * 4];
        ((float4*)(out + (row0 + t2 * 16) * 16))[lane] = vo;
    }
    #pragma unroll
    for (int t2 = 0; t2 < 2; ++t2) {
        const float a = __shfl(ljacc[t2 * 2 + 0], (lane & 7) * 8);
        const float b = __shfl(ljacc[t2 * 2 + 1], (lane & 7) * 8);
        if (lane < 16)
            out[(size_t)B_N * 16 + row0 + t2 * 16 + lane] = (lane < 8) ? a : b;
    }
}

extern "C" void kernel_launch(void* const* d_in, const int* in_sizes, int n_in,
                              void* d_out, int out_size, void* d_ws, size_t ws_size,
                              hipStream_t stream) {
    const float* x     = (const float*)d_in[0];
    const float* c     = (const float*)d_in[1];
    const float* W1s   = (const float*)d_in[2];
    const float* b1s   = (const float*)d_in[3];
    const float* Whs   = (const float*)d_in[4];
    const float* bhs   = (const float*)d_in[5];
    const float* Wos   = (const float*)d_in[6];
    const float* bos   = (const float*)d_in[7];
    const int*   perms = (const int*)d_in[8];
    float* out = (float*)d_out;
    _Float16* ws = (_Float16*)d_ws;

    prep_kernel<<<dim3(416), dim3(64), 0, stream>>>(W1s, b1s, Whs, Wos, ws);
    flow_mfma<<<dim3(B_N / 32), dim3(64), 0, stream>>>(
        x, c, bhs, bos, perms, ws, out);
}